// Round 1
// baseline (527.389 us; speedup 1.0000x reference)
//
#include <hip/hip_runtime.h>
#include <hip/hip_bf16.h>

typedef __attribute__((ext_vector_type(8))) short short8;
typedef __attribute__((ext_vector_type(4))) float floatx4;
typedef unsigned short u16;

#define D 256
#define BM 128

__device__ __forceinline__ short f2bf(float f) {
    return __builtin_bit_cast(short, __float2bfloat16(f));
}

// W1 fp32 [k][n] -> W1T bf16 [n][k]  (so B-fragments are 16B-contiguous in k)
__global__ void w1t_kernel(const float* __restrict__ W1, u16* __restrict__ W1T) {
    __shared__ float tile[32][33];
    const int k0 = blockIdx.x * 32, n0 = blockIdx.y * 32;
    const int tx = threadIdx.x, ty = threadIdx.y; // 32 x 8
#pragma unroll
    for (int i = 0; i < 32; i += 8)
        tile[ty + i][tx] = W1[(long)(k0 + ty + i) * D + (n0 + tx)];
    __syncthreads();
#pragma unroll
    for (int i = 0; i < 32; i += 8) {
        float f = tile[tx][ty + i];                 // = W1[k0+tx][n0+ty+i]
        W1T[(long)(n0 + ty + i) * D + (k0 + tx)] = (u16)f2bf(f);
    }
}

// Fused: z = forces@W1 (bf16 MFMA, fp32 accum); h=silu(z+b1); s=h@W2+b2;
// scatter-add s*V_st into out[idx_t].
__launch_bounds__(256, 2)
__global__ void head_kernel(const float* __restrict__ forces,
                            const float* __restrict__ V_st,
                            const u16*   __restrict__ W1T,
                            const float* __restrict__ b1,
                            const float* __restrict__ W2,
                            const float* __restrict__ b2,
                            const int*   __restrict__ idx_t,
                            float* __restrict__ out,
                            int E) {
    const int tid  = threadIdx.x;
    const int lane = tid & 63;
    const int w    = tid >> 6;
    const int wm   = w >> 1;      // row half: 0..1
    const int wn   = w & 1;       // col half: 0..1
    const int l15  = lane & 15;
    const int g    = lane >> 4;   // 0..3

    const long blk_row = (long)blockIdx.x * BM;
    const int  base_n  = wn * 128;

    floatx4 acc[4][8];
#pragma unroll
    for (int mr = 0; mr < 4; ++mr)
#pragma unroll
        for (int nc = 0; nc < 8; ++nc)
            acc[mr][nc] = (floatx4){0.f, 0.f, 0.f, 0.f};

    // A-fragment base pointers: lane holds A[row = l15][k = g*8 + j]
    const float* aptr[4];
#pragma unroll
    for (int mr = 0; mr < 4; ++mr) {
        long row = blk_row + wm * 64 + mr * 16 + l15;
        if (row > (long)E - 1) row = (long)E - 1;   // tail clamp (harmless garbage, masked later)
        aptr[mr] = forces + row * D + g * 8;
    }
    // B-fragment base pointers: lane holds B[k = g*8 + j][col = l15] via W1T[col][k]
    const u16* bptr[8];
#pragma unroll
    for (int nc = 0; nc < 8; ++nc) {
        int n = base_n + nc * 16 + l15;
        bptr[nc] = W1T + (long)n * D + g * 8;
    }

#pragma unroll
    for (int k0 = 0; k0 < D; k0 += 32) {
        short8 af[4];
#pragma unroll
        for (int mr = 0; mr < 4; ++mr) {
            floatx4 f0 = *(const floatx4*)(aptr[mr] + k0);
            floatx4 f1 = *(const floatx4*)(aptr[mr] + k0 + 4);
            short8 a;
#pragma unroll
            for (int j = 0; j < 4; ++j) { a[j] = f2bf(f0[j]); a[4 + j] = f2bf(f1[j]); }
            af[mr] = a;
        }
        short8 bfr[8];
#pragma unroll
        for (int nc = 0; nc < 8; ++nc)
            bfr[nc] = *(const short8*)(bptr[nc] + k0);
#pragma unroll
        for (int mr = 0; mr < 4; ++mr)
#pragma unroll
            for (int nc = 0; nc < 8; ++nc)
                acc[mr][nc] = __builtin_amdgcn_mfma_f32_16x16x32_bf16(
                    af[mr], bfr[nc], acc[mr][nc], 0, 0, 0);
    }

    // Epilogue: silu(z + b1) dot W2, per lane over its 8 col-tiles.
    float b1v[8], w2v[8];
#pragma unroll
    for (int nc = 0; nc < 8; ++nc) {
        int n = base_n + nc * 16 + l15;
        b1v[nc] = b1[n];
        w2v[nc] = W2[n];
    }
    float part[4][4];  // [mr][reg]; row = wm*64 + mr*16 + g*4 + reg, C/D layout per m89
#pragma unroll
    for (int mr = 0; mr < 4; ++mr)
#pragma unroll
        for (int r = 0; r < 4; ++r) {
            float s = 0.f;
#pragma unroll
            for (int nc = 0; nc < 8; ++nc) {
                float z = acc[mr][nc][r] + b1v[nc];
                float h = z / (1.f + __expf(-z));
                s += h * w2v[nc];
            }
            part[mr][r] = s;
        }

    // reduce across the 16 lanes (cols) sharing a row
#pragma unroll
    for (int off = 1; off < 16; off <<= 1)
#pragma unroll
        for (int mr = 0; mr < 4; ++mr)
#pragma unroll
            for (int r = 0; r < 4; ++r)
                part[mr][r] += __shfl_xor(part[mr][r], off, 16);

    __shared__ float s_lds[2][BM];
    if (l15 == 0) {
#pragma unroll
        for (int mr = 0; mr < 4; ++mr)
#pragma unroll
            for (int r = 0; r < 4; ++r)
                s_lds[wn][wm * 64 + mr * 16 + g * 4 + r] = part[mr][r];
    }
    __syncthreads();

    if (tid < BM) {
        long e = blk_row + tid;
        if (e < E) {
            float s = s_lds[0][tid] + s_lds[1][tid] + b2[0];
            float vx = V_st[e * 3 + 0], vy = V_st[e * 3 + 1], vz = V_st[e * 3 + 2];
            long node = (long)idx_t[e];
            atomicAdd(&out[node * 3 + 0], s * vx);
            atomicAdd(&out[node * 3 + 1], s * vy);
            atomicAdd(&out[node * 3 + 2], s * vz);
        }
    }
}

extern "C" void kernel_launch(void* const* d_in, const int* in_sizes, int n_in,
                              void* d_out, int out_size, void* d_ws, size_t ws_size,
                              hipStream_t stream) {
    const float* forces = (const float*)d_in[0];
    const float* V_st   = (const float*)d_in[1];
    const float* W1     = (const float*)d_in[2];
    const float* b1     = (const float*)d_in[3];
    const float* W2     = (const float*)d_in[4];
    const float* b2     = (const float*)d_in[5];
    const int*   idx    = (const int*)d_in[6];
    const int E = in_sizes[6];

    u16* W1T = (u16*)d_ws;  // 256*256*2 = 131072 B

    hipMemsetAsync(d_out, 0, (size_t)out_size * sizeof(float), stream);
    w1t_kernel<<<dim3(8, 8), dim3(32, 8), 0, stream>>>(W1, W1T);
    const int grid = (E + BM - 1) / BM;
    head_kernel<<<grid, 256, 0, stream>>>(forces, V_st, W1T, b1, W2, b2, idx,
                                          (float*)d_out, E);
}

// Round 3
// 298.746 us; speedup vs baseline: 1.7653x; 1.7653x over previous
//
#include <hip/hip_runtime.h>
#include <hip/hip_bf16.h>

typedef __attribute__((ext_vector_type(8))) short short8;
typedef __attribute__((ext_vector_type(4))) float floatx4;
typedef unsigned short u16;

#define D 256
#define BM 128
#define NT 512

__device__ __forceinline__ short f2bf(float f) {
    return __builtin_bit_cast(short, __float2bfloat16(f));
}

// W1 fp32 [k][n] -> W1F bf16, MFMA-fragment-major:
// W1F[((k0t*16 + nt)*64 + lane)*8 + j] = W1[k0t*32 + (lane>>4)*8 + j][nt*16 + (lane&15)]
// so a wave's B-fragment load for (k0t, nt) is lane-contiguous: lane reads 16B at lane*16.
__global__ void w1f_kernel(const float* __restrict__ W1, u16* __restrict__ W1F) {
    const int k = blockIdx.x, n = threadIdx.x;
    const int k0t = k >> 5, g = (k >> 3) & 3, j = k & 7;
    const int nt = n >> 4, l15 = n & 15;
    W1F[(long)((((k0t << 4) + nt) << 6) + (g << 4) + l15) * 8 + j] = (u16)f2bf(W1[k * D + n]);
}

// Fused: z = forces@W1 (bf16 MFMA, fp32 accum); h=silu(z+b1); s=h@W2+b2;
// scatter-add s*V_st into out[idx_t].
__launch_bounds__(NT, 4)
__global__ void head_kernel(const float* __restrict__ forces,
                            const float* __restrict__ V_st,
                            const u16*   __restrict__ W1F,
                            const float* __restrict__ b1,
                            const float* __restrict__ W2,
                            const float* __restrict__ b2,
                            const int*   __restrict__ idx_t,
                            float* __restrict__ out,
                            int E) {
    __shared__ u16 Abuf[BM * D];     // 64 KiB, XOR-swizzled bf16 A tile
    __shared__ float s_red[4][BM];   // 2 KiB cross-wave scalar reduce

    const int tid  = threadIdx.x;
    const int lane = tid & 63;
    const int w    = tid >> 6;       // 0..7
    const int wm   = w >> 2;         // row half 0..1
    const int wn   = w & 3;          // col quarter 0..3
    const int l15  = lane & 15;
    const int g    = lane >> 4;      // 0..3

    const long blk_row = (long)blockIdx.x * BM;

    // ---- stage A: 128 rows x 1KB, contiguous & coalesced; fp32 -> bf16 -> swizzled LDS ----
#pragma unroll
    for (int it = 0; it < 8; ++it) {
        int c   = it * NT + tid;     // chunk of 8 floats, 0..4095
        int row = c >> 5;            // 32 chunks per row
        int kc  = (c & 31) * 8;
        long grow = blk_row + row;
        if (grow > (long)E - 1) grow = (long)E - 1;   // tail clamp (E%BM==0: never taken)
        const float* src = forces + grow * D + kc;
        floatx4 f0 = *(const floatx4*)(src);
        floatx4 f1 = *(const floatx4*)(src + 4);
        short8 a;
#pragma unroll
        for (int jj = 0; jj < 4; ++jj) { a[jj] = f2bf(f0[jj]); a[4 + jj] = f2bf(f1[jj]); }
        int off = (row * 512 + kc * 2) ^ ((row & 7) << 4);
        *(short8*)((char*)Abuf + off) = a;
    }
    __syncthreads();

    // ---- MFMA: each wave owns 64 rows x 64 cols = 4x4 fragments, K in 8 steps of 32 ----
    floatx4 acc[4][4];
#pragma unroll
    for (int mr = 0; mr < 4; ++mr)
#pragma unroll
        for (int nc = 0; nc < 4; ++nc)
            acc[mr][nc] = (floatx4){0.f, 0.f, 0.f, 0.f};

#pragma unroll
    for (int k0t = 0; k0t < 8; ++k0t) {
        short8 af[4], bfr[4];
#pragma unroll
        for (int mr = 0; mr < 4; ++mr) {
            int row = wm * 64 + mr * 16 + l15;
            int off = (row * 512 + k0t * 64 + g * 16) ^ ((row & 7) << 4);
            af[mr] = *(const short8*)((const char*)Abuf + off);
        }
#pragma unroll
        for (int nc = 0; nc < 4; ++nc) {
            int nt = wn * 4 + nc;
            bfr[nc] = *(const short8*)(W1F + (long)((k0t * 16 + nt) * 64 + lane) * 8);
        }
#pragma unroll
        for (int mr = 0; mr < 4; ++mr)
#pragma unroll
            for (int nc = 0; nc < 4; ++nc)
                acc[mr][nc] = __builtin_amdgcn_mfma_f32_16x16x32_bf16(
                    af[mr], bfr[nc], acc[mr][nc], 0, 0, 0);
    }

    // ---- epilogue: silu(z + b1) dot W2 over this wave's 64 cols ----
    float b1v[4], w2v[4];
#pragma unroll
    for (int nc = 0; nc < 4; ++nc) {
        int n = wn * 64 + nc * 16 + l15;
        b1v[nc] = b1[n];
        w2v[nc] = W2[n];
    }
    float part[4][4];  // [mr][reg]; C/D: col=lane&15, row=(lane>>4)*4+reg (m89)
#pragma unroll
    for (int mr = 0; mr < 4; ++mr)
#pragma unroll
        for (int r = 0; r < 4; ++r) {
            float s = 0.f;
#pragma unroll
            for (int nc = 0; nc < 4; ++nc) {
                float z = acc[mr][nc][r] + b1v[nc];
                float h = z / (1.f + __expf(-z));
                s += h * w2v[nc];
            }
            part[mr][r] = s;
        }

    // reduce across the 16 lanes (cols) sharing each row
#pragma unroll
    for (int off = 1; off < 16; off <<= 1)
#pragma unroll
        for (int mr = 0; mr < 4; ++mr)
#pragma unroll
            for (int r = 0; r < 4; ++r)
                part[mr][r] += __shfl_xor(part[mr][r], off, 16);

    if (l15 == 0) {
#pragma unroll
        for (int mr = 0; mr < 4; ++mr)
#pragma unroll
            for (int r = 0; r < 4; ++r)
                s_red[wn][wm * 64 + mr * 16 + g * 4 + r] = part[mr][r];
    }
    __syncthreads();

    // ---- scalar per edge + scatter ----
    if (tid < BM) {
        long e = blk_row + tid;
        if (e < E) {
            float s = s_red[0][tid] + s_red[1][tid] + s_red[2][tid] + s_red[3][tid] + b2[0];
            float vx = V_st[e * 3 + 0], vy = V_st[e * 3 + 1], vz = V_st[e * 3 + 2];
            long node = (long)idx_t[e];
            atomicAdd(&out[node * 3 + 0], s * vx);
            atomicAdd(&out[node * 3 + 1], s * vy);
            atomicAdd(&out[node * 3 + 2], s * vz);
        }
    }
}

extern "C" void kernel_launch(void* const* d_in, const int* in_sizes, int n_in,
                              void* d_out, int out_size, void* d_ws, size_t ws_size,
                              hipStream_t stream) {
    const float* forces = (const float*)d_in[0];
    const float* V_st   = (const float*)d_in[1];
    const float* W1     = (const float*)d_in[2];
    const float* b1     = (const float*)d_in[3];
    const float* W2     = (const float*)d_in[4];
    const float* b2     = (const float*)d_in[5];
    const int*   idx    = (const int*)d_in[6];
    const int E = in_sizes[6];

    u16* W1F = (u16*)d_ws;  // 256*256*2 = 131072 B

    hipMemsetAsync(d_out, 0, (size_t)out_size * sizeof(float), stream);
    w1f_kernel<<<D, D, 0, stream>>>(W1, W1F);
    const int grid = (E + BM - 1) / BM;
    head_kernel<<<grid, NT, 0, stream>>>(forces, V_st, W1F, b1, W2, b2, idx,
                                         (float*)d_out, E);
}